// Round 11
// baseline (932.007 us; speedup 1.0000x reference)
//
#include <hip/hip_runtime.h>
#include <hip/hip_bf16.h>

typedef __attribute__((ext_vector_type(8))) short bf16x8_t;
typedef __attribute__((ext_vector_type(4))) float f32x4_t;
typedef unsigned short u16;
typedef unsigned int u32;

// async global->LDS, 16B per lane; LDS dest must be wave-uniform base (+lane*16)
#define GLL16(gp, lp) \
    __builtin_amdgcn_global_load_lds((const __attribute__((address_space(1))) u32*)(gp), \
                                     (__attribute__((address_space(3))) u32*)(lp), 16, 0, 0)

__device__ __forceinline__ float bf2f(unsigned int u16v) {
    union { unsigned int i; float f; } c;
    c.i = (u16v & 0xffffu) << 16;
    return c.f;
}
__device__ __forceinline__ unsigned short f2bf(float f) {
    union { float f; unsigned int i; } c; c.f = f;
    unsigned int x = c.i;
    unsigned int r = (x + 0x7fffu + ((x >> 16) & 1u)) >> 16;
    return (unsigned short)r;
}

// ---------------- cast kernels ----------------

// both x inputs -> bf16 in one launch
__global__ void cast_x2_kernel(const float* __restrict__ x1, const float* __restrict__ x2,
                               u16* __restrict__ h1, u16* __restrict__ h2, int n4) {
    int i = blockIdx.x * blockDim.x + threadIdx.x;
    int stride = gridDim.x * blockDim.x;
    for (; i < n4; i += stride) {
        float4 v = *(const float4*)(x1 + (size_t)i * 4);
        ushort4 h;
        h.x = f2bf(v.x); h.y = f2bf(v.y); h.z = f2bf(v.z); h.w = f2bf(v.w);
        *(ushort4*)(h1 + (size_t)i * 4) = h;
        v = *(const float4*)(x2 + (size_t)i * 4);
        h.x = f2bf(v.x); h.y = f2bf(v.y); h.z = f2bf(v.z); h.w = f2bf(v.w);
        *(ushort4*)(h2 + (size_t)i * 4) = h;
    }
}

// 4 gate weights [K][N] f32 -> [N][K] bf16, z selects which
__global__ __launch_bounds__(256) void cast_wt4_kernel(
    const float* __restrict__ W0, const float* __restrict__ W1,
    const float* __restrict__ W2, const float* __restrict__ W3,
    u16* __restrict__ T0, u16* __restrict__ T1,
    u16* __restrict__ T2, u16* __restrict__ T3,
    int K, int N) {
    const float* W = (blockIdx.z == 0) ? W0 : (blockIdx.z == 1) ? W1 : (blockIdx.z == 2) ? W2 : W3;
    u16* Wt = (blockIdx.z == 0) ? T0 : (blockIdx.z == 1) ? T1 : (blockIdx.z == 2) ? T2 : T3;
    __shared__ u16 tile[32][33];
    int c0 = blockIdx.x * 32, k0 = blockIdx.y * 32;
    int tx = threadIdx.x & 31, ty = threadIdx.x >> 5;
#pragma unroll
    for (int i = 0; i < 4; ++i) {
        int k = k0 + ty + i * 8;
        tile[ty + i * 8][tx] = f2bf(W[(size_t)k * N + c0 + tx]);
    }
    __syncthreads();
#pragma unroll
    for (int i = 0; i < 4; ++i) {
        int c = c0 + ty + i * 8;
        Wt[(size_t)c * K + k0 + tx] = tile[tx][ty + i * 8];
    }
}

// kv weights: W [K][N] f32 -> Wt [N][K] bf16 hi + lo; z selects Wkv1/Wkv2
__global__ __launch_bounds__(256) void cast_wt_split2_kernel(
    const float* __restrict__ W0, const float* __restrict__ W1,
    u16* __restrict__ H0, u16* __restrict__ L0,
    u16* __restrict__ H1, u16* __restrict__ L1,
    int K, int N) {
    const float* W = blockIdx.z ? W1 : W0;
    u16* Wh = blockIdx.z ? H1 : H0;
    u16* Wl = blockIdx.z ? L1 : L0;
    __shared__ u16 th[32][33];
    __shared__ u16 tl[32][33];
    int c0 = blockIdx.x * 32, k0 = blockIdx.y * 32;
    int tx = threadIdx.x & 31, ty = threadIdx.x >> 5;
#pragma unroll
    for (int i = 0; i < 4; ++i) {
        int k = k0 + ty + i * 8;
        float f = W[(size_t)k * N + c0 + tx];
        unsigned short h = f2bf(f);
        th[ty + i * 8][tx] = h;
        tl[ty + i * 8][tx] = f2bf(f - bf2f(h));
    }
    __syncthreads();
#pragma unroll
    for (int i = 0; i < 4; ++i) {
        int c = c0 + ty + i * 8;
        Wh[(size_t)c * K + k0 + tx] = th[tx][ty + i * 8];
        Wl[(size_t)c * K + k0 + tx] = tl[tx][ty + i * 8];
    }
}

// ---------------- 128x128 GEMM: BK=32, DOUBLE-buffered GLL, post-barrier stage ----------------
// All matrices: row stride 1024 bf16 elements. M = 16384.
// EPI 0: C=A@B + bias, relu -> bf16 out_bf [M][N], N=1024
// EPI 1: C=A@B + bias, sigmoid -> f32 out_f [M][N], N=1024
// EPI 2: 2-term packed-K kv (K=2048 = Ah@Bh + Ah@Bl), N=2048:
//        col<1024 -> kout f32; col>=1024 -> gate_vg *= C (in place).
//        A-slice s=kt>>1 shared by kt pairs; A dbuf'd on pairs (As[s&1]),
//        next slice staged at even kt.
//
// Pipeline: per iter: __syncthreads() (drains loads issued a FULL ITER ago ->
// cheap) -> stage kt+1 into the ^1 buffers (WAR-safe: last read in iter kt-1,
// complete before this barrier) -> ds_reads + 16 MFMA on tile kt.
// LDS 32 KB/block; __launch_bounds__(256,4) -> 3-4 blocks/CU for cross-block
// MFMA overlap (m114). Swizzle: chunk (row,q) holds global chunk q^((row>>1)&3);
// frag ds_read_b128 lands 2 lanes/bank (free, verified 0 conflicts R9/R10).

__device__ __forceinline__ void stage32(u16* lds_buf, const u16* __restrict__ gbase, int tid) {
#pragma unroll
    for (int g = 0; g < 2; ++g) {
        int c = tid + g * 256;
        int row = c >> 2, qp = c & 3;
        int qs = qp ^ ((row >> 1) & 3);
        GLL16(gbase + (size_t)row * 1024 + qs * 8, lds_buf + c * 8);
    }
}

template <int EPI>
__global__ __launch_bounds__(256, 4) void gemm128_kernel(
    const u16* __restrict__ Ah,
    const u16* __restrict__ Bh, const u16* __restrict__ Bl,
    const float* __restrict__ bias,
    u16* __restrict__ out_bf, float* __restrict__ out_f,
    float* __restrict__ gate_vg, float* __restrict__ kout,
    int N)
{
    __shared__ u16 As[2][4096];  // 8 KB each
    __shared__ u16 Bs[2][4096];
    const int NT = (EPI == 2) ? 64 : 32;

    // XCD-aware block swizzle (nwg divisible by 8)
    int nwg = 128 * (N >> 7);
    int wg = blockIdx.y * 128 + blockIdx.x;
    int cpx = nwg >> 3;
    wg = (wg & 7) * cpx + (wg >> 3);
    int bx = wg & 127, by = wg >> 7;
    int row0 = bx << 7, col0 = by << 7;

    const int tid = threadIdx.x;
    const int lane = tid & 63;
    const int w = tid >> 6;
    const int wm = w >> 1, wn = w & 1;           // 2x2 waves, 64x64 each
    const int fr = lane & 15, fq = lane >> 4;    // frag row, k-chunk

    const u16* Ab0 = Ah + (size_t)row0 * 1024;
    auto aslice = [&](int s) { return Ab0 + s * 32; };
    auto bbase = [&](int kt) -> const u16* {
        if (EPI == 2) return ((kt & 1) ? Bl : Bh) + (size_t)col0 * 1024 + (kt >> 1) * 32;
        return Bh + (size_t)col0 * 1024 + kt * 32;
    };

    f32x4_t acc[4][4];
#pragma unroll
    for (int m = 0; m < 4; ++m)
#pragma unroll
        for (int n = 0; n < 4; ++n) acc[m][n] = (f32x4_t)(0.0f);

    // read offsets (u16 units): row stride 32; slot = fq ^ ((row>>1)&3)
    const int slot = (fq ^ ((fr >> 1) & 3)) * 8;
    int aoff[4], boff[4];
#pragma unroll
    for (int m = 0; m < 4; ++m) aoff[m] = (wm * 64 + m * 16 + fr) * 32 + slot;
#pragma unroll
    for (int n = 0; n < 4; ++n) boff[n] = (wn * 64 + n * 16 + fr) * 32 + slot;

    // prologue: stage tile 0
    stage32(As[0], aslice(0), tid);
    stage32(Bs[0], bbase(0), tid);

    for (int kt = 0; kt < NT; ++kt) {
        __syncthreads();   // drains loads issued one full iter ago + barrier

        // stage tile kt+1 into the OTHER buffers (WAR-safe post-barrier)
        if (kt + 1 < NT) {
            stage32(Bs[(kt + 1) & 1], bbase(kt + 1), tid);
            if (EPI == 2) {
                int s1 = (kt >> 1) + 1;
                if ((kt & 1) == 0 && s1 < 32)
                    stage32(As[s1 & 1], aslice(s1), tid);   // consumed at kt=2*s1
            } else {
                stage32(As[(kt + 1) & 1], aslice(kt + 1), tid);
            }
        }

        const int ab = (EPI == 2) ? ((kt >> 1) & 1) : (kt & 1);
        const int bb = kt & 1;
        bf16x8_t a[4], b[4];
#pragma unroll
        for (int m = 0; m < 4; ++m) a[m] = *(const bf16x8_t*)&As[ab][aoff[m]];
#pragma unroll
        for (int n = 0; n < 4; ++n) b[n] = *(const bf16x8_t*)&Bs[bb][boff[n]];
#pragma unroll
        for (int m = 0; m < 4; ++m)
#pragma unroll
            for (int n = 0; n < 4; ++n)
                acc[m][n] = __builtin_amdgcn_mfma_f32_16x16x32_bf16(a[m], b[n], acc[m][n], 0, 0, 0);
    }

    // ---- epilogue ----
#pragma unroll
    for (int m = 0; m < 4; ++m) {
        int row = row0 + wm * 64 + m * 16 + fq * 4;
#pragma unroll
        for (int n = 0; n < 4; ++n) {
            int col = col0 + wn * 64 + n * 16 + fr;
            if (EPI == 0) {
                float bv = bias[col];
#pragma unroll
                for (int rr = 0; rr < 4; ++rr)
                    out_bf[(size_t)(row + rr) * N + col] = f2bf(fmaxf(acc[m][n][rr] + bv, 0.0f));
            } else if (EPI == 1) {
                float bv = bias[col];
#pragma unroll
                for (int rr = 0; rr < 4; ++rr)
                    out_f[(size_t)(row + rr) * N + col] = 1.0f / (1.0f + __expf(-(acc[m][n][rr] + bv)));
            } else {
                if (col < 1024) {
#pragma unroll
                    for (int rr = 0; rr < 4; ++rr)
                        kout[(size_t)(row + rr) * 1024 + col] = acc[m][n][rr];
                } else {
#pragma unroll
                    for (int rr = 0; rr < 4; ++rr) {
                        size_t idx = (size_t)(row + rr) * 1024 + (col - 1024);
                        gate_vg[idx] = acc[m][n][rr] * gate_vg[idx];
                    }
                }
            }
        }
    }
}

// ---------------- ctx partials: part[p][bh][d][e] = sum_{n in chunk} k[n,d]*vg[n,e] ----------------
__global__ __launch_bounds__(256) void ctx_part_kernel(
    const float* __restrict__ kmat,
    const float* __restrict__ vmat,
    float* __restrict__ part)
{
    int bh = blockIdx.x & 63;
    int p  = blockIdx.x >> 6;
    int b = bh >> 4, h = bh & 15;
    int n0 = p * 512;
    __shared__ float ks[128][64];
    __shared__ float vs[128][64];
    int t = threadIdx.x;
    int dg = t & 15, eg = t >> 4;
    float acc[4][4];
#pragma unroll
    for (int i = 0; i < 4; ++i)
#pragma unroll
        for (int j = 0; j < 4; ++j) acc[i][j] = 0.0f;

    const float* kb = kmat + (size_t)b * 4096 * 1024 + h * 64;
    const float* vb = vmat + (size_t)b * 4096 * 1024 + h * 64;

    for (int c0 = 0; c0 < 512; c0 += 128) {
        __syncthreads();
#pragma unroll
        for (int s = 0; s < 8; ++s) {
            int ci = t + s * 256;
            int r = ci >> 4, o4 = (ci & 15) * 4;
            size_t g = (size_t)(n0 + c0 + r) * 1024 + o4;
            *(float4*)(&ks[r][o4]) = *(const float4*)(kb + g);
            *(float4*)(&vs[r][o4]) = *(const float4*)(vb + g);
        }
        __syncthreads();
#pragma unroll 4
        for (int n = 0; n < 128; ++n) {
            float4 k4 = *(const float4*)(&ks[n][dg * 4]);
            float4 v4 = *(const float4*)(&vs[n][eg * 4]);
            acc[0][0] += k4.x * v4.x; acc[0][1] += k4.x * v4.y; acc[0][2] += k4.x * v4.z; acc[0][3] += k4.x * v4.w;
            acc[1][0] += k4.y * v4.x; acc[1][1] += k4.y * v4.y; acc[1][2] += k4.y * v4.z; acc[1][3] += k4.y * v4.w;
            acc[2][0] += k4.z * v4.x; acc[2][1] += k4.z * v4.y; acc[2][2] += k4.z * v4.z; acc[2][3] += k4.z * v4.w;
            acc[3][0] += k4.w * v4.x; acc[3][1] += k4.w * v4.y; acc[3][2] += k4.w * v4.z; acc[3][3] += k4.w * v4.w;
        }
    }
    float* pp = part + ((size_t)(p * 64 + bh)) * 64 * 64;
#pragma unroll
    for (int i = 0; i < 4; ++i)
#pragma unroll
        for (int j = 0; j < 4; ++j)
            pp[(dg * 4 + i) * 64 + (eg * 4 + j)] = acc[i][j];
}

// ---------------- reduce partials + scale + column softmax (over d), 256 thr ----------------
__global__ __launch_bounds__(256) void softmax_ctx_kernel(const float* __restrict__ part,
                                                          float* __restrict__ ctx) {
    int bh = blockIdx.x;
    int t = threadIdx.x;
    int e = t & 63, dq = t >> 6;
    __shared__ float red[4][68];
    float loc[16];
    float m = -1e30f;
#pragma unroll
    for (int i = 0; i < 16; ++i) {
        int d = dq * 16 + i;
        float s = 0.f;
#pragma unroll
        for (int p = 0; p < 8; ++p)
            s += part[(((size_t)(p * 64 + bh)) * 64 + d) * 64 + e];
        s *= 0.125f;
        loc[i] = s;
        m = fmaxf(m, s);
    }
    red[dq][e] = m;
    __syncthreads();
    float M = fmaxf(fmaxf(red[0][e], red[1][e]), fmaxf(red[2][e], red[3][e]));
    float sum = 0.f;
#pragma unroll
    for (int i = 0; i < 16; ++i) {
        float v = __expf(loc[i] - M);
        loc[i] = v;
        sum += v;
    }
    __syncthreads();
    red[dq][e] = sum;
    __syncthreads();
    float inv = 1.0f / (red[0][e] + red[1][e] + red[2][e] + red[3][e]);
#pragma unroll
    for (int i = 0; i < 16; ++i) {
        int d = dq * 16 + i;
        ctx[((size_t)bh * 64 + d) * 64 + e] = loc[i] * inv;
    }
}

// ---------------- output (both streams): o_s[b,n,h*64+e] = sum_d x_s[...d] * ctx[...] ----------------
__global__ __launch_bounds__(256) void out_gemm_kernel(
    const float* __restrict__ x1, const float* __restrict__ x2,
    const float* __restrict__ ctxA,   // used by stream 1 (= ctx2)
    const float* __restrict__ ctxB,   // used by stream 2 (= ctx1)
    float* __restrict__ out)
{
    int id = blockIdx.x;
    int s = id >> 12;
    int r = id & 4095;
    int nc = r & 63;
    int h = (r >> 6) & 15;
    int b = r >> 10;
    const float* x = s ? x2 : x1;
    const float* ctx = s ? ctxB : ctxA;
    float* o = out + (size_t)s * 16777216;
    size_t r0 = (size_t)b * 4096 + nc * 64;
    __shared__ float xs[64][65];
    __shared__ float cs[64][64];
    int t = threadIdx.x;
    for (int idx = t; idx < 4096; idx += 256) {
        int rr = idx >> 6, d = idx & 63;
        xs[rr][d] = x[(r0 + rr) * 1024 + h * 64 + d];
    }
    const float* cb = ctx + ((size_t)(b * 16 + h)) * 4096;
    for (int idx = t; idx < 4096; idx += 256) {
        cs[idx >> 6][idx & 63] = cb[idx];
    }
    __syncthreads();
    int eg = t & 15, nl = t >> 4;
    for (int rr = nl; rr < 64; rr += 16) {
        float a0 = 0.f, a1 = 0.f, a2 = 0.f, a3 = 0.f;
#pragma unroll
        for (int d = 0; d < 64; ++d) {
            float xv = xs[rr][d];
            float4 cv = *(const float4*)(&cs[d][eg * 4]);
            a0 += xv * cv.x; a1 += xv * cv.y; a2 += xv * cv.z; a3 += xv * cv.w;
        }
        float4 ov = make_float4(a0, a1, a2, a3);
        *(float4*)(&o[(r0 + rr) * 1024 + h * 64 + eg * 4]) = ov;
    }
}

// ---------------- host ----------------

extern "C" void kernel_launch(void* const* d_in, const int* in_sizes, int n_in,
                              void* d_out, int out_size, void* d_ws, size_t ws_size,
                              hipStream_t stream)
{
    (void)in_sizes; (void)n_in; (void)out_size; (void)ws_size;
    const float* x1   = (const float*)d_in[0];
    const float* x2   = (const float*)d_in[1];
    const float* Wkv1 = (const float*)d_in[2];
    const float* Wkv2 = (const float*)d_in[3];
    const float* g1w1 = (const float*)d_in[4];
    const float* g1b1 = (const float*)d_in[5];
    const float* g1w2 = (const float*)d_in[6];
    const float* g1b2 = (const float*)d_in[7];
    const float* g2w1 = (const float*)d_in[8];
    const float* g2b1 = (const float*)d_in[9];
    const float* g2w2 = (const float*)d_in[10];
    const float* g2b2 = (const float*)d_in[11];
    float* out = (float*)d_out;

    char* ws = (char*)d_ws;
    size_t off = 0;
    auto alloc = [&](size_t b) { void* p = ws + off; off += (b + 255) & ~(size_t)255; return p; };
    const size_t NTOK = 16384;
    u16* xh1   = (u16*)alloc(NTOK * 1024 * 2);
    u16* xh2   = (u16*)alloc(NTOK * 1024 * 2);
    u16* wkv1h = (u16*)alloc((size_t)2048 * 1024 * 2);
    u16* wkv1l = (u16*)alloc((size_t)2048 * 1024 * 2);
    u16* wkv2h = (u16*)alloc((size_t)2048 * 1024 * 2);
    u16* wkv2l = (u16*)alloc((size_t)2048 * 1024 * 2);
    u16* g1w1t = (u16*)alloc((size_t)1024 * 1024 * 2);
    u16* g1w2t = (u16*)alloc((size_t)1024 * 1024 * 2);
    u16* g2w1t = (u16*)alloc((size_t)1024 * 1024 * 2);
    u16* g2w2t = (u16*)alloc((size_t)1024 * 1024 * 2);
    u16* hbuf  = (u16*)alloc(NTOK * 1024 * 2);
    float* gate = (float*)alloc(NTOK * 1024 * 4);  // gate, then vg in place
    float* kbuf = (float*)alloc(NTOK * 1024 * 4);
    float* part = (float*)alloc((size_t)8 * 64 * 64 * 64 * 4);
    float* ctx1 = (float*)alloc((size_t)64 * 64 * 64 * 4);
    float* ctx2 = (float*)alloc((size_t)64 * 64 * 64 * 4);

    // weights (merged launches)
    cast_wt_split2_kernel<<<dim3(64, 32, 2), 256, 0, stream>>>(Wkv1, Wkv2,
                                                               wkv1h, wkv1l, wkv2h, wkv2l, 1024, 2048);
    cast_wt4_kernel<<<dim3(32, 32, 4), 256, 0, stream>>>(g1w1, g1w2, g2w1, g2w2,
                                                         g1w1t, g1w2t, g2w1t, g2w2t, 1024, 1024);
    // both x casts in one launch
    cast_x2_kernel<<<2048, 256, 0, stream>>>(x1, x2, xh1, xh2, (int)(NTOK * 1024 / 4));

    // ---- stream 1 ----
    gemm128_kernel<0><<<dim3(128, 8), 256, 0, stream>>>(xh1, g1w1t, nullptr, g1b1,
                                                        hbuf, nullptr, nullptr, nullptr, 1024);
    gemm128_kernel<1><<<dim3(128, 8), 256, 0, stream>>>(hbuf, g1w2t, nullptr, g1b2,
                                                        nullptr, gate, nullptr, nullptr, 1024);
    gemm128_kernel<2><<<dim3(128, 16), 256, 0, stream>>>(xh1, wkv1h, wkv1l, nullptr,
                                                         nullptr, nullptr, gate, kbuf, 2048);
    ctx_part_kernel<<<512, 256, 0, stream>>>(kbuf, gate, part);
    softmax_ctx_kernel<<<64, 256, 0, stream>>>(part, ctx1);

    // ---- stream 2 ----
    gemm128_kernel<0><<<dim3(128, 8), 256, 0, stream>>>(xh2, g2w1t, nullptr, g2b1,
                                                        hbuf, nullptr, nullptr, nullptr, 1024);
    gemm128_kernel<1><<<dim3(128, 8), 256, 0, stream>>>(hbuf, g2w2t, nullptr, g2b2,
                                                        nullptr, gate, nullptr, nullptr, 1024);
    gemm128_kernel<2><<<dim3(128, 16), 256, 0, stream>>>(xh2, wkv2h, wkv2l, nullptr,
                                                         nullptr, nullptr, gate, kbuf, 2048);
    ctx_part_kernel<<<512, 256, 0, stream>>>(kbuf, gate, part);
    softmax_ctx_kernel<<<64, 256, 0, stream>>>(part, ctx2);

    // ---- outputs, both streams in one launch (cross: o1 uses ctx2, o2 uses ctx1) ----
    out_gemm_kernel<<<8192, 256, 0, stream>>>(x1, x2, ctx2, ctx1, out);
}

// Round 12
// 757.968 us; speedup vs baseline: 1.2296x; 1.2296x over previous
//
#include <hip/hip_runtime.h>
#include <hip/hip_bf16.h>

typedef __attribute__((ext_vector_type(8))) short bf16x8_t;
typedef __attribute__((ext_vector_type(4))) float f32x4_t;
typedef unsigned short u16;
typedef unsigned int u32;

// async global->LDS, 16B per lane; LDS dest must be wave-uniform base (+lane*16)
#define GLL16(gp, lp) \
    __builtin_amdgcn_global_load_lds((const __attribute__((address_space(1))) u32*)(gp), \
                                     (__attribute__((address_space(3))) u32*)(lp), 16, 0, 0)

__device__ __forceinline__ float bf2f(unsigned int u16v) {
    union { unsigned int i; float f; } c;
    c.i = (u16v & 0xffffu) << 16;
    return c.f;
}
__device__ __forceinline__ unsigned short f2bf(float f) {
    union { float f; unsigned int i; } c; c.f = f;
    unsigned int x = c.i;
    unsigned int r = (x + 0x7fffu + ((x >> 16) & 1u)) >> 16;
    return (unsigned short)r;
}

// ---------------- cast kernels ----------------

// both x inputs -> bf16 in one launch
__global__ void cast_x2_kernel(const float* __restrict__ x1, const float* __restrict__ x2,
                               u16* __restrict__ h1, u16* __restrict__ h2, int n4) {
    int i = blockIdx.x * blockDim.x + threadIdx.x;
    int stride = gridDim.x * blockDim.x;
    for (; i < n4; i += stride) {
        float4 v = *(const float4*)(x1 + (size_t)i * 4);
        ushort4 h;
        h.x = f2bf(v.x); h.y = f2bf(v.y); h.z = f2bf(v.z); h.w = f2bf(v.w);
        *(ushort4*)(h1 + (size_t)i * 4) = h;
        v = *(const float4*)(x2 + (size_t)i * 4);
        h.x = f2bf(v.x); h.y = f2bf(v.y); h.z = f2bf(v.z); h.w = f2bf(v.w);
        *(ushort4*)(h2 + (size_t)i * 4) = h;
    }
}

// 4 gate weights [K][N] f32 -> [N][K] bf16, z selects which
__global__ __launch_bounds__(256) void cast_wt4_kernel(
    const float* __restrict__ W0, const float* __restrict__ W1,
    const float* __restrict__ W2, const float* __restrict__ W3,
    u16* __restrict__ T0, u16* __restrict__ T1,
    u16* __restrict__ T2, u16* __restrict__ T3,
    int K, int N) {
    const float* W = (blockIdx.z == 0) ? W0 : (blockIdx.z == 1) ? W1 : (blockIdx.z == 2) ? W2 : W3;
    u16* Wt = (blockIdx.z == 0) ? T0 : (blockIdx.z == 1) ? T1 : (blockIdx.z == 2) ? T2 : T3;
    __shared__ u16 tile[32][33];
    int c0 = blockIdx.x * 32, k0 = blockIdx.y * 32;
    int tx = threadIdx.x & 31, ty = threadIdx.x >> 5;
#pragma unroll
    for (int i = 0; i < 4; ++i) {
        int k = k0 + ty + i * 8;
        tile[ty + i * 8][tx] = f2bf(W[(size_t)k * N + c0 + tx]);
    }
    __syncthreads();
#pragma unroll
    for (int i = 0; i < 4; ++i) {
        int c = c0 + ty + i * 8;
        Wt[(size_t)c * K + k0 + tx] = tile[tx][ty + i * 8];
    }
}

// kv weights: W [K][N] f32 -> Wt [N][K] bf16 hi + lo; z selects Wkv1/Wkv2
__global__ __launch_bounds__(256) void cast_wt_split2_kernel(
    const float* __restrict__ W0, const float* __restrict__ W1,
    u16* __restrict__ H0, u16* __restrict__ L0,
    u16* __restrict__ H1, u16* __restrict__ L1,
    int K, int N) {
    const float* W = blockIdx.z ? W1 : W0;
    u16* Wh = blockIdx.z ? H1 : H0;
    u16* Wl = blockIdx.z ? L1 : L0;
    __shared__ u16 th[32][33];
    __shared__ u16 tl[32][33];
    int c0 = blockIdx.x * 32, k0 = blockIdx.y * 32;
    int tx = threadIdx.x & 31, ty = threadIdx.x >> 5;
#pragma unroll
    for (int i = 0; i < 4; ++i) {
        int k = k0 + ty + i * 8;
        float f = W[(size_t)k * N + c0 + tx];
        unsigned short h = f2bf(f);
        th[ty + i * 8][tx] = h;
        tl[ty + i * 8][tx] = f2bf(f - bf2f(h));
    }
    __syncthreads();
#pragma unroll
    for (int i = 0; i < 4; ++i) {
        int c = c0 + ty + i * 8;
        Wh[(size_t)c * K + k0 + tx] = th[tx][ty + i * 8];
        Wl[(size_t)c * K + k0 + tx] = tl[tx][ty + i * 8];
    }
}

// ---------------- 128x128 GEMM: BK=32, double-buffered GLL, post-barrier stage ----------------
// All matrices: row stride 1024 bf16 elements. M = 16384.
// EPI 0: C=A@B + bias, relu -> bf16 out_bf [M][N], N=1024
// EPI 1: C=A@B + bias, sigmoid -> f32 out_f [M][N], N=1024
// EPI 2: 2-term packed-K kv (K=2048 = Ah@Bh + Ah@Bl), N=2048:
//        col<1024 -> kout f32; col>=1024 -> gate_vg *= C (in place).

__device__ __forceinline__ void stage32(u16* lds_buf, const u16* __restrict__ gbase, int tid) {
#pragma unroll
    for (int g = 0; g < 2; ++g) {
        int c = tid + g * 256;
        int row = c >> 2, qp = c & 3;
        int qs = qp ^ ((row >> 1) & 3);
        GLL16(gbase + (size_t)row * 1024 + qs * 8, lds_buf + c * 8);
    }
}

template <int EPI>
__global__ __launch_bounds__(256, 4) void gemm128_kernel(
    const u16* __restrict__ Ah,
    const u16* __restrict__ Bh, const u16* __restrict__ Bl,
    const float* __restrict__ bias,
    u16* __restrict__ out_bf, float* __restrict__ out_f,
    float* __restrict__ gate_vg, float* __restrict__ kout,
    int N)
{
    __shared__ u16 As[2][4096];  // 8 KB each
    __shared__ u16 Bs[2][4096];
    const int NT = (EPI == 2) ? 64 : 32;

    // XCD-aware block swizzle (nwg divisible by 8)
    int nwg = 128 * (N >> 7);
    int wg = blockIdx.y * 128 + blockIdx.x;
    int cpx = nwg >> 3;
    wg = (wg & 7) * cpx + (wg >> 3);
    int bx = wg & 127, by = wg >> 7;
    int row0 = bx << 7, col0 = by << 7;

    const int tid = threadIdx.x;
    const int lane = tid & 63;
    const int w = tid >> 6;
    const int wm = w >> 1, wn = w & 1;           // 2x2 waves, 64x64 each
    const int fr = lane & 15, fq = lane >> 4;    // frag row, k-chunk

    const u16* Ab0 = Ah + (size_t)row0 * 1024;
    auto aslice = [&](int s) { return Ab0 + s * 32; };
    auto bbase = [&](int kt) -> const u16* {
        if (EPI == 2) return ((kt & 1) ? Bl : Bh) + (size_t)col0 * 1024 + (kt >> 1) * 32;
        return Bh + (size_t)col0 * 1024 + kt * 32;
    };

    f32x4_t acc[4][4];
#pragma unroll
    for (int m = 0; m < 4; ++m)
#pragma unroll
        for (int n = 0; n < 4; ++n) acc[m][n] = (f32x4_t)(0.0f);

    // read offsets (u16 units): row stride 32; slot = fq ^ ((row>>1)&3)
    const int slot = (fq ^ ((fr >> 1) & 3)) * 8;
    int aoff[4], boff[4];
#pragma unroll
    for (int m = 0; m < 4; ++m) aoff[m] = (wm * 64 + m * 16 + fr) * 32 + slot;
#pragma unroll
    for (int n = 0; n < 4; ++n) boff[n] = (wn * 64 + n * 16 + fr) * 32 + slot;

    // prologue: stage tile 0
    stage32(As[0], aslice(0), tid);
    stage32(Bs[0], bbase(0), tid);

    for (int kt = 0; kt < NT; ++kt) {
        __syncthreads();   // drains loads issued one full iter ago + barrier

        // stage tile kt+1 into the OTHER buffers (WAR-safe post-barrier)
        if (kt + 1 < NT) {
            stage32(Bs[(kt + 1) & 1], bbase(kt + 1), tid);
            if (EPI == 2) {
                int s1 = (kt >> 1) + 1;
                if ((kt & 1) == 0 && s1 < 32)
                    stage32(As[s1 & 1], aslice(s1), tid);   // consumed at kt=2*s1
            } else {
                stage32(As[(kt + 1) & 1], aslice(kt + 1), tid);
            }
        }

        const int ab = (EPI == 2) ? ((kt >> 1) & 1) : (kt & 1);
        const int bb = kt & 1;
        bf16x8_t a[4], b[4];
#pragma unroll
        for (int m = 0; m < 4; ++m) a[m] = *(const bf16x8_t*)&As[ab][aoff[m]];
#pragma unroll
        for (int n = 0; n < 4; ++n) b[n] = *(const bf16x8_t*)&Bs[bb][boff[n]];
#pragma unroll
        for (int m = 0; m < 4; ++m)
#pragma unroll
            for (int n = 0; n < 4; ++n)
                acc[m][n] = __builtin_amdgcn_mfma_f32_16x16x32_bf16(a[m], b[n], acc[m][n], 0, 0, 0);
    }

    // ---- epilogue ----
#pragma unroll
    for (int m = 0; m < 4; ++m) {
        int row = row0 + wm * 64 + m * 16 + fq * 4;
#pragma unroll
        for (int n = 0; n < 4; ++n) {
            int col = col0 + wn * 64 + n * 16 + fr;
            if (EPI == 0) {
                float bv = bias[col];
#pragma unroll
                for (int rr = 0; rr < 4; ++rr)
                    out_bf[(size_t)(row + rr) * N + col] = f2bf(fmaxf(acc[m][n][rr] + bv, 0.0f));
            } else if (EPI == 1) {
                float bv = bias[col];
#pragma unroll
                for (int rr = 0; rr < 4; ++rr)
                    out_f[(size_t)(row + rr) * N + col] = 1.0f / (1.0f + __expf(-(acc[m][n][rr] + bv)));
            } else {
                if (col < 1024) {
#pragma unroll
                    for (int rr = 0; rr < 4; ++rr)
                        kout[(size_t)(row + rr) * 1024 + col] = acc[m][n][rr];
                } else {
#pragma unroll
                    for (int rr = 0; rr < 4; ++rr) {
                        size_t idx = (size_t)(row + rr) * 1024 + (col - 1024);
                        gate_vg[idx] = acc[m][n][rr] * gate_vg[idx];
                    }
                }
            }
        }
    }
}

// ---------------- ctx partials: part[p][bh][d][e] = sum_{n in chunk} k[n,d]*vg[n,e] ----------------
__global__ __launch_bounds__(256) void ctx_part_kernel(
    const float* __restrict__ kmat,
    const float* __restrict__ vmat,
    float* __restrict__ part)
{
    int bh = blockIdx.x & 63;
    int p  = blockIdx.x >> 6;
    int b = bh >> 4, h = bh & 15;
    int n0 = p * 512;
    __shared__ float ks[128][64];
    __shared__ float vs[128][64];
    int t = threadIdx.x;
    int dg = t & 15, eg = t >> 4;
    float acc[4][4];
#pragma unroll
    for (int i = 0; i < 4; ++i)
#pragma unroll
        for (int j = 0; j < 4; ++j) acc[i][j] = 0.0f;

    const float* kb = kmat + (size_t)b * 4096 * 1024 + h * 64;
    const float* vb = vmat + (size_t)b * 4096 * 1024 + h * 64;

    for (int c0 = 0; c0 < 512; c0 += 128) {
        __syncthreads();
#pragma unroll
        for (int s = 0; s < 8; ++s) {
            int ci = t + s * 256;
            int r = ci >> 4, o4 = (ci & 15) * 4;
            size_t g = (size_t)(n0 + c0 + r) * 1024 + o4;
            *(float4*)(&ks[r][o4]) = *(const float4*)(kb + g);
            *(float4*)(&vs[r][o4]) = *(const float4*)(vb + g);
        }
        __syncthreads();
#pragma unroll 4
        for (int n = 0; n < 128; ++n) {
            float4 k4 = *(const float4*)(&ks[n][dg * 4]);
            float4 v4 = *(const float4*)(&vs[n][eg * 4]);
            acc[0][0] += k4.x * v4.x; acc[0][1] += k4.x * v4.y; acc[0][2] += k4.x * v4.z; acc[0][3] += k4.x * v4.w;
            acc[1][0] += k4.y * v4.x; acc[1][1] += k4.y * v4.y; acc[1][2] += k4.y * v4.z; acc[1][3] += k4.y * v4.w;
            acc[2][0] += k4.z * v4.x; acc[2][1] += k4.z * v4.y; acc[2][2] += k4.z * v4.z; acc[2][3] += k4.z * v4.w;
            acc[3][0] += k4.w * v4.x; acc[3][1] += k4.w * v4.y; acc[3][2] += k4.w * v4.z; acc[3][3] += k4.w * v4.w;
        }
    }
    float* pp = part + ((size_t)(p * 64 + bh)) * 64 * 64;
#pragma unroll
    for (int i = 0; i < 4; ++i)
#pragma unroll
        for (int j = 0; j < 4; ++j)
            pp[(dg * 4 + i) * 64 + (eg * 4 + j)] = acc[i][j];
}

// ---------------- reduce partials + scale + column softmax; write ctx^T in bf16 ----------------
// ctxT[(bh*64 + e)*64 + d] = softmax_d(ctx[d][e])  -- the Bt[N][K] layout for out MFMA
__global__ __launch_bounds__(256) void softmax_ctx_kernel(const float* __restrict__ part,
                                                          u16* __restrict__ ctxT) {
    int bh = blockIdx.x;
    int t = threadIdx.x;
    int e = t & 63, dq = t >> 6;
    __shared__ float red[4][68];
    float loc[16];
    float m = -1e30f;
#pragma unroll
    for (int i = 0; i < 16; ++i) {
        int d = dq * 16 + i;
        float s = 0.f;
#pragma unroll
        for (int p = 0; p < 8; ++p)
            s += part[(((size_t)(p * 64 + bh)) * 64 + d) * 64 + e];
        s *= 0.125f;
        loc[i] = s;
        m = fmaxf(m, s);
    }
    red[dq][e] = m;
    __syncthreads();
    float M = fmaxf(fmaxf(red[0][e], red[1][e]), fmaxf(red[2][e], red[3][e]));
    float sum = 0.f;
#pragma unroll
    for (int i = 0; i < 16; ++i) {
        float v = __expf(loc[i] - M);
        loc[i] = v;
        sum += v;
    }
    __syncthreads();
    red[dq][e] = sum;
    __syncthreads();
    float inv = 1.0f / (red[0][e] + red[1][e] + red[2][e] + red[3][e]);
    u16* op = ctxT + ((size_t)bh * 64 + e) * 64 + dq * 16;
#pragma unroll
    for (int i = 0; i < 16; ++i)
        op[i] = f2bf(loc[i] * inv);
}

// ---------------- output via MFMA: o[n, h*64+e] = sum_d x[n, h*64+d] * ctx[d][e] ----------------
// Per block: one (stream, b, h, 256-row chunk); 4 waves, each 64 rows x 64 cols, K=64.
// A = xh bf16 (row stride 1024), Bt = ctxT bf16 [e][d] (row stride 64). No LDS/barriers;
// fragments read straight from global (ctxT is L2-hot; x read 64B-contiguous per row).
__global__ __launch_bounds__(256) void out_mfma_kernel(
    const u16* __restrict__ xh1, const u16* __restrict__ xh2,
    const u16* __restrict__ ctxTA,   // stream 1 uses ctx2^T
    const u16* __restrict__ ctxTB,   // stream 2 uses ctx1^T
    float* __restrict__ out)
{
    int id = blockIdx.x;
    int s = id >> 10;
    int r = id & 1023;
    int b = r >> 8;          // 4
    int h = (r >> 4) & 15;   // 16
    int rc = r & 15;         // 16 row-chunks of 256
    const u16* xh = s ? xh2 : xh1;
    const u16* ctxT = s ? ctxTB : ctxTA;
    float* o = out + (size_t)s * 16777216;

    int tid = threadIdx.x, lane = tid & 63, w = tid >> 6;
    int fr = lane & 15, fq = lane >> 4;
    size_t rowbase = (size_t)b * 4096 + rc * 256 + w * 64;
    const u16* Ab = xh + rowbase * 1024 + h * 64;
    const u16* Bb = ctxT + ((size_t)(b * 16 + h)) * 4096;

    f32x4_t acc[4][4];
#pragma unroll
    for (int m = 0; m < 4; ++m)
#pragma unroll
        for (int n = 0; n < 4; ++n) acc[m][n] = (f32x4_t)(0.0f);

#pragma unroll
    for (int ks = 0; ks < 2; ++ks) {
        bf16x8_t a[4], bfr[4];
#pragma unroll
        for (int m = 0; m < 4; ++m)
            a[m] = *(const bf16x8_t*)(Ab + (size_t)(m * 16 + fr) * 1024 + ks * 32 + fq * 8);
#pragma unroll
        for (int n = 0; n < 4; ++n)
            bfr[n] = *(const bf16x8_t*)(Bb + (n * 16 + fr) * 64 + ks * 32 + fq * 8);
#pragma unroll
        for (int m = 0; m < 4; ++m)
#pragma unroll
            for (int n = 0; n < 4; ++n)
                acc[m][n] = __builtin_amdgcn_mfma_f32_16x16x32_bf16(a[m], bfr[n], acc[m][n], 0, 0, 0);
    }

#pragma unroll
    for (int m = 0; m < 4; ++m) {
#pragma unroll
        for (int n = 0; n < 4; ++n) {
            int col = h * 64 + n * 16 + fr;
#pragma unroll
            for (int rr = 0; rr < 4; ++rr) {
                size_t row = rowbase + m * 16 + fq * 4 + rr;
                o[row * 1024 + col] = acc[m][n][rr];
            }
        }
    }
}

// ---------------- host ----------------

extern "C" void kernel_launch(void* const* d_in, const int* in_sizes, int n_in,
                              void* d_out, int out_size, void* d_ws, size_t ws_size,
                              hipStream_t stream)
{
    (void)in_sizes; (void)n_in; (void)out_size; (void)ws_size;
    const float* x1   = (const float*)d_in[0];
    const float* x2   = (const float*)d_in[1];
    const float* Wkv1 = (const float*)d_in[2];
    const float* Wkv2 = (const float*)d_in[3];
    const float* g1w1 = (const float*)d_in[4];
    const float* g1b1 = (const float*)d_in[5];
    const float* g1w2 = (const float*)d_in[6];
    const float* g1b2 = (const float*)d_in[7];
    const float* g2w1 = (const float*)d_in[8];
    const float* g2b1 = (const float*)d_in[9];
    const float* g2w2 = (const float*)d_in[10];
    const float* g2b2 = (const float*)d_in[11];
    float* out = (float*)d_out;

    char* ws = (char*)d_ws;
    size_t off = 0;
    auto alloc = [&](size_t b) { void* p = ws + off; off += (b + 255) & ~(size_t)255; return p; };
    const size_t NTOK = 16384;
    u16* xh1   = (u16*)alloc(NTOK * 1024 * 2);
    u16* xh2   = (u16*)alloc(NTOK * 1024 * 2);
    u16* wkv1h = (u16*)alloc((size_t)2048 * 1024 * 2);
    u16* wkv1l = (u16*)alloc((size_t)2048 * 1024 * 2);
    u16* wkv2h = (u16*)alloc((size_t)2048 * 1024 * 2);
    u16* wkv2l = (u16*)alloc((size_t)2048 * 1024 * 2);
    u16* g1w1t = (u16*)alloc((size_t)1024 * 1024 * 2);
    u16* g1w2t = (u16*)alloc((size_t)1024 * 1024 * 2);
    u16* g2w1t = (u16*)alloc((size_t)1024 * 1024 * 2);
    u16* g2w2t = (u16*)alloc((size_t)1024 * 1024 * 2);
    u16* hbuf  = (u16*)alloc(NTOK * 1024 * 2);
    float* gate = (float*)alloc(NTOK * 1024 * 4);  // gate, then vg in place
    float* kbuf = (float*)alloc(NTOK * 1024 * 4);
    float* part = (float*)alloc((size_t)8 * 64 * 64 * 64 * 4);
    u16* ctxT1 = (u16*)alloc((size_t)64 * 64 * 64 * 2);
    u16* ctxT2 = (u16*)alloc((size_t)64 * 64 * 64 * 2);

    // weights (merged launches)
    cast_wt_split2_kernel<<<dim3(64, 32, 2), 256, 0, stream>>>(Wkv1, Wkv2,
                                                               wkv1h, wkv1l, wkv2h, wkv2l, 1024, 2048);
    cast_wt4_kernel<<<dim3(32, 32, 4), 256, 0, stream>>>(g1w1, g1w2, g2w1, g2w2,
                                                         g1w1t, g1w2t, g2w1t, g2w2t, 1024, 1024);
    cast_x2_kernel<<<2048, 256, 0, stream>>>(x1, x2, xh1, xh2, (int)(NTOK * 1024 / 4));

    // ---- stream 1 ----
    gemm128_kernel<0><<<dim3(128, 8), 256, 0, stream>>>(xh1, g1w1t, nullptr, g1b1,
                                                        hbuf, nullptr, nullptr, nullptr, 1024);
    gemm128_kernel<1><<<dim3(128, 8), 256, 0, stream>>>(hbuf, g1w2t, nullptr, g1b2,
                                                        nullptr, gate, nullptr, nullptr, 1024);
    gemm128_kernel<2><<<dim3(128, 16), 256, 0, stream>>>(xh1, wkv1h, wkv1l, nullptr,
                                                         nullptr, nullptr, gate, kbuf, 2048);
    ctx_part_kernel<<<512, 256, 0, stream>>>(kbuf, gate, part);
    softmax_ctx_kernel<<<64, 256, 0, stream>>>(part, ctxT1);

    // ---- stream 2 ----
    gemm128_kernel<0><<<dim3(128, 8), 256, 0, stream>>>(xh2, g2w1t, nullptr, g2b1,
                                                        hbuf, nullptr, nullptr, nullptr, 1024);
    gemm128_kernel<1><<<dim3(128, 8), 256, 0, stream>>>(hbuf, g2w2t, nullptr, g2b2,
                                                        nullptr, gate, nullptr, nullptr, 1024);
    gemm128_kernel<2><<<dim3(128, 16), 256, 0, stream>>>(xh2, wkv2h, wkv2l, nullptr,
                                                         nullptr, nullptr, gate, kbuf, 2048);
    ctx_part_kernel<<<512, 256, 0, stream>>>(kbuf, gate, part);
    softmax_ctx_kernel<<<64, 256, 0, stream>>>(part, ctxT2);

    // ---- outputs, both streams in one launch (cross: o1 uses ctx2, o2 uses ctx1) ----
    out_mfma_kernel<<<2048, 256, 0, stream>>>(xh1, xh2, ctxT2, ctxT1, out);
}

// Round 15
// 755.093 us; speedup vs baseline: 1.2343x; 1.0038x over previous
//
#include <hip/hip_runtime.h>
#include <hip/hip_bf16.h>

typedef __attribute__((ext_vector_type(8))) short bf16x8_t;
typedef __attribute__((ext_vector_type(4))) float f32x4_t;
typedef unsigned short u16;
typedef unsigned int u32;

// async global->LDS, 16B per lane; LDS dest must be wave-uniform base (+lane*16)
#define GLL16(gp, lp) \
    __builtin_amdgcn_global_load_lds((const __attribute__((address_space(1))) u32*)(gp), \
                                     (__attribute__((address_space(3))) u32*)(lp), 16, 0, 0)

__device__ __forceinline__ float bf2f(unsigned int u16v) {
    union { unsigned int i; float f; } c;
    c.i = (u16v & 0xffffu) << 16;
    return c.f;
}
__device__ __forceinline__ unsigned short f2bf(float f) {
    union { float f; unsigned int i; } c; c.f = f;
    unsigned int x = c.i;
    unsigned int r = (x + 0x7fffu + ((x >> 16) & 1u)) >> 16;
    return (unsigned short)r;
}

// ---------------- cast kernels ----------------

__global__ void cast_x2_kernel(const float* __restrict__ x1, const float* __restrict__ x2,
                               u16* __restrict__ h1, u16* __restrict__ h2, int n4) {
    int i = blockIdx.x * blockDim.x + threadIdx.x;
    int stride = gridDim.x * blockDim.x;
    for (; i < n4; i += stride) {
        float4 v = *(const float4*)(x1 + (size_t)i * 4);
        ushort4 h;
        h.x = f2bf(v.x); h.y = f2bf(v.y); h.z = f2bf(v.z); h.w = f2bf(v.w);
        *(ushort4*)(h1 + (size_t)i * 4) = h;
        v = *(const float4*)(x2 + (size_t)i * 4);
        h.x = f2bf(v.x); h.y = f2bf(v.y); h.z = f2bf(v.z); h.w = f2bf(v.w);
        *(ushort4*)(h2 + (size_t)i * 4) = h;
    }
}

// 4 gate weights [K][N] f32 -> [N][K] bf16, z selects which
__global__ __launch_bounds__(256) void cast_wt4_kernel(
    const float* __restrict__ W0, const float* __restrict__ W1,
    const float* __restrict__ W2, const float* __restrict__ W3,
    u16* __restrict__ T0, u16* __restrict__ T1,
    u16* __restrict__ T2, u16* __restrict__ T3,
    int K, int N) {
    const float* W = (blockIdx.z == 0) ? W0 : (blockIdx.z == 1) ? W1 : (blockIdx.z == 2) ? W2 : W3;
    u16* Wt = (blockIdx.z == 0) ? T0 : (blockIdx.z == 1) ? T1 : (blockIdx.z == 2) ? T2 : T3;
    __shared__ u16 tile[32][33];
    int c0 = blockIdx.x * 32, k0 = blockIdx.y * 32;
    int tx = threadIdx.x & 31, ty = threadIdx.x >> 5;
#pragma unroll
    for (int i = 0; i < 4; ++i) {
        int k = k0 + ty + i * 8;
        tile[ty + i * 8][tx] = f2bf(W[(size_t)k * N + c0 + tx]);
    }
    __syncthreads();
#pragma unroll
    for (int i = 0; i < 4; ++i) {
        int c = c0 + ty + i * 8;
        Wt[(size_t)c * K + k0 + tx] = tile[tx][ty + i * 8];
    }
}

// kv weights: W [K][N] f32 -> Wt [N][K] bf16 hi + lo; z selects Wkv1/Wkv2
__global__ __launch_bounds__(256) void cast_wt_split2_kernel(
    const float* __restrict__ W0, const float* __restrict__ W1,
    u16* __restrict__ H0, u16* __restrict__ L0,
    u16* __restrict__ H1, u16* __restrict__ L1,
    int K, int N) {
    const float* W = blockIdx.z ? W1 : W0;
    u16* Wh = blockIdx.z ? H1 : H0;
    u16* Wl = blockIdx.z ? L1 : L0;
    __shared__ u16 th[32][33];
    __shared__ u16 tl[32][33];
    int c0 = blockIdx.x * 32, k0 = blockIdx.y * 32;
    int tx = threadIdx.x & 31, ty = threadIdx.x >> 5;
#pragma unroll
    for (int i = 0; i < 4; ++i) {
        int k = k0 + ty + i * 8;
        float f = W[(size_t)k * N + c0 + tx];
        unsigned short h = f2bf(f);
        th[ty + i * 8][tx] = h;
        tl[ty + i * 8][tx] = f2bf(f - bf2f(h));
    }
    __syncthreads();
#pragma unroll
    for (int i = 0; i < 4; ++i) {
        int c = c0 + ty + i * 8;
        Wh[(size_t)c * K + k0 + tx] = th[tx][ty + i * 8];
        Wl[(size_t)c * K + k0 + tx] = tl[tx][ty + i * 8];
    }
}

// ---------------- 128x128 GEMM: BK=32, double-buffered GLL, post-barrier stage ----------------
// All matrices: row stride 1024 bf16 elements. M = 16384.
// EPI 0: C=A@B + bias, relu -> bf16 out_bf [M][N], N=1024
// EPI 1: C=A@B + bias, sigmoid -> f32 out_f [M][N], N=1024
// EPI 2: 2-term packed-K kv (K=2048 = Ah@Bh + Ah@Bl), N=2048:
//        col<1024 -> kout f32; col>=1024 -> gate_vg *= C (in place, f32).
//        A slice shared per kt pair (staged on even kt only).

__device__ __forceinline__ void stage32(u16* lds_buf, const u16* __restrict__ gbase, int tid) {
#pragma unroll
    for (int g = 0; g < 2; ++g) {
        int c = tid + g * 256;
        int row = c >> 2, qp = c & 3;
        int qs = qp ^ ((row >> 1) & 3);
        GLL16(gbase + (size_t)row * 1024 + qs * 8, lds_buf + c * 8);
    }
}

template <int EPI>
__global__ __launch_bounds__(256, 4) void gemm128_kernel(
    const u16* __restrict__ Ah,
    const u16* __restrict__ Bh, const u16* __restrict__ Bl,
    const float* __restrict__ bias,
    u16* __restrict__ out_bf, float* __restrict__ out_f,
    float* __restrict__ gate_vg, float* __restrict__ kout,
    int N)
{
    __shared__ u16 As[2][4096];  // 8 KB each
    __shared__ u16 Bs[2][4096];
    const int NT = (EPI == 2) ? 64 : 32;

    // XCD-aware block swizzle (nwg divisible by 8)
    int nwg = 128 * (N >> 7);
    int wg = blockIdx.y * 128 + blockIdx.x;
    int cpx = nwg >> 3;
    wg = (wg & 7) * cpx + (wg >> 3);
    int bx = wg & 127, by = wg >> 7;
    int row0 = bx << 7, col0 = by << 7;

    const int tid = threadIdx.x;
    const int lane = tid & 63;
    const int w = tid >> 6;
    const int wm = w >> 1, wn = w & 1;           // 2x2 waves, 64x64 each
    const int fr = lane & 15, fq = lane >> 4;    // frag row, k-chunk

    const u16* Ab0 = Ah + (size_t)row0 * 1024;
    auto aslice = [&](int s) { return Ab0 + s * 32; };
    auto bbase = [&](int kt) -> const u16* {
        if (EPI == 2) return ((kt & 1) ? Bl : Bh) + (size_t)col0 * 1024 + (kt >> 1) * 32;
        return Bh + (size_t)col0 * 1024 + kt * 32;
    };

    f32x4_t acc[4][4];
#pragma unroll
    for (int m = 0; m < 4; ++m)
#pragma unroll
        for (int n = 0; n < 4; ++n) acc[m][n] = (f32x4_t)(0.0f);

    // read offsets (u16 units): row stride 32; slot = fq ^ ((row>>1)&3)
    const int slot = (fq ^ ((fr >> 1) & 3)) * 8;
    int aoff[4], boff[4];
#pragma unroll
    for (int m = 0; m < 4; ++m) aoff[m] = (wm * 64 + m * 16 + fr) * 32 + slot;
#pragma unroll
    for (int n = 0; n < 4; ++n) boff[n] = (wn * 64 + n * 16 + fr) * 32 + slot;

    // prologue: stage tile 0
    stage32(As[0], aslice(0), tid);
    stage32(Bs[0], bbase(0), tid);

    for (int kt = 0; kt < NT; ++kt) {
        __syncthreads();   // drains loads issued one full iter ago + barrier

        // stage tile kt+1 into the OTHER buffers (WAR-safe post-barrier)
        if (kt + 1 < NT) {
            stage32(Bs[(kt + 1) & 1], bbase(kt + 1), tid);
            if (EPI == 2) {
                int s1 = (kt >> 1) + 1;
                if ((kt & 1) == 0 && s1 < 32)
                    stage32(As[s1 & 1], aslice(s1), tid);   // consumed at kt=2*s1
            } else {
                stage32(As[(kt + 1) & 1], aslice(kt + 1), tid);
            }
        }

        const int ab = (EPI == 2) ? ((kt >> 1) & 1) : (kt & 1);
        const int bb = kt & 1;
        bf16x8_t a[4], b[4];
#pragma unroll
        for (int m = 0; m < 4; ++m) a[m] = *(const bf16x8_t*)&As[ab][aoff[m]];
#pragma unroll
        for (int n = 0; n < 4; ++n) b[n] = *(const bf16x8_t*)&Bs[bb][boff[n]];
#pragma unroll
        for (int m = 0; m < 4; ++m)
#pragma unroll
            for (int n = 0; n < 4; ++n)
                acc[m][n] = __builtin_amdgcn_mfma_f32_16x16x32_bf16(a[m], b[n], acc[m][n], 0, 0, 0);
    }

    // ---- epilogue ----
#pragma unroll
    for (int m = 0; m < 4; ++m) {
        int row = row0 + wm * 64 + m * 16 + fq * 4;
#pragma unroll
        for (int n = 0; n < 4; ++n) {
            int col = col0 + wn * 64 + n * 16 + fr;
            if (EPI == 0) {
                float bv = bias[col];
#pragma unroll
                for (int rr = 0; rr < 4; ++rr)
                    out_bf[(size_t)(row + rr) * N + col] = f2bf(fmaxf(acc[m][n][rr] + bv, 0.0f));
            } else if (EPI == 1) {
                float bv = bias[col];
#pragma unroll
                for (int rr = 0; rr < 4; ++rr)
                    out_f[(size_t)(row + rr) * N + col] = 1.0f / (1.0f + __expf(-(acc[m][n][rr] + bv)));
            } else {
                if (col < 1024) {
#pragma unroll
                    for (int rr = 0; rr < 4; ++rr)
                        kout[(size_t)(row + rr) * 1024 + col] = acc[m][n][rr];
                } else {
                    int e = col - 1024;
#pragma unroll
                    for (int rr = 0; rr < 4; ++rr) {
                        size_t idx = (size_t)(row + rr) * 1024 + e;
                        gate_vg[idx] = acc[m][n][rr] * gate_vg[idx];
                    }
                }
            }
        }
    }
}

// ---------------- ctx partials (f32): part[p][bh][d][e] = sum_{n in chunk} k[n,d]*vg[n,e] ----------------
__global__ __launch_bounds__(256) void ctx_part_kernel(
    const float* __restrict__ kmat,
    const float* __restrict__ vmat,
    float* __restrict__ part)
{
    int bh = blockIdx.x & 63;
    int p  = blockIdx.x >> 6;
    int b = bh >> 4, h = bh & 15;
    int n0 = p * 512;
    __shared__ float ks[128][64];
    __shared__ float vs[128][64];
    int t = threadIdx.x;
    int dg = t & 15, eg = t >> 4;
    float acc[4][4];
#pragma unroll
    for (int i = 0; i < 4; ++i)
#pragma unroll
        for (int j = 0; j < 4; ++j) acc[i][j] = 0.0f;

    const float* kb = kmat + (size_t)b * 4096 * 1024 + h * 64;
    const float* vb = vmat + (size_t)b * 4096 * 1024 + h * 64;

    for (int c0 = 0; c0 < 512; c0 += 128) {
        __syncthreads();
#pragma unroll
        for (int s = 0; s < 8; ++s) {
            int ci = t + s * 256;
            int r = ci >> 4, o4 = (ci & 15) * 4;
            size_t g = (size_t)(n0 + c0 + r) * 1024 + o4;
            *(float4*)(&ks[r][o4]) = *(const float4*)(kb + g);
            *(float4*)(&vs[r][o4]) = *(const float4*)(vb + g);
        }
        __syncthreads();
#pragma unroll 4
        for (int n = 0; n < 128; ++n) {
            float4 k4 = *(const float4*)(&ks[n][dg * 4]);
            float4 v4 = *(const float4*)(&vs[n][eg * 4]);
            acc[0][0] += k4.x * v4.x; acc[0][1] += k4.x * v4.y; acc[0][2] += k4.x * v4.z; acc[0][3] += k4.x * v4.w;
            acc[1][0] += k4.y * v4.x; acc[1][1] += k4.y * v4.y; acc[1][2] += k4.y * v4.z; acc[1][3] += k4.y * v4.w;
            acc[2][0] += k4.z * v4.x; acc[2][1] += k4.z * v4.y; acc[2][2] += k4.z * v4.z; acc[2][3] += k4.z * v4.w;
            acc[3][0] += k4.w * v4.x; acc[3][1] += k4.w * v4.y; acc[3][2] += k4.w * v4.z; acc[3][3] += k4.w * v4.w;
        }
    }
    float* pp = part + ((size_t)(p * 64 + bh)) * 64 * 64;
#pragma unroll
    for (int i = 0; i < 4; ++i)
#pragma unroll
        for (int j = 0; j < 4; ++j)
            pp[(dg * 4 + i) * 64 + (eg * 4 + j)] = acc[i][j];
}

// ---------------- reduce + scale + column softmax; write ctx^T in bf16 ----------------
// ctxT[(bh*64 + e)*64 + d] = softmax_d(ctx[d][e])  -- the Bt[N][K] layout for out MFMA
__global__ __launch_bounds__(256) void softmax_ctx_kernel(const float* __restrict__ part,
                                                          u16* __restrict__ ctxT) {
    int bh = blockIdx.x;
    int t = threadIdx.x;
    int e = t & 63, dq = t >> 6;
    __shared__ float red[4][68];
    float loc[16];
    float m = -1e30f;
#pragma unroll
    for (int i = 0; i < 16; ++i) {
        int d = dq * 16 + i;
        float s = 0.f;
#pragma unroll
        for (int p = 0; p < 8; ++p)
            s += part[(((size_t)(p * 64 + bh)) * 64 + d) * 64 + e];
        s *= 0.125f;
        loc[i] = s;
        m = fmaxf(m, s);
    }
    red[dq][e] = m;
    __syncthreads();
    float M = fmaxf(fmaxf(red[0][e], red[1][e]), fmaxf(red[2][e], red[3][e]));
    float sum = 0.f;
#pragma unroll
    for (int i = 0; i < 16; ++i) {
        float v = __expf(loc[i] - M);
        loc[i] = v;
        sum += v;
    }
    __syncthreads();
    red[dq][e] = sum;
    __syncthreads();
    float inv = 1.0f / (red[0][e] + red[1][e] + red[2][e] + red[3][e]);
    u16* op = ctxT + ((size_t)bh * 64 + e) * 64 + dq * 16;
#pragma unroll
    for (int i = 0; i < 16; ++i)
        op[i] = f2bf(loc[i] * inv);
}

// ---------------- output via MFMA: o[n, h*64+e] = sum_d x[n, h*64+d] * ctx[d][e] ----------------
__global__ __launch_bounds__(256) void out_mfma_kernel(
    const u16* __restrict__ xh1, const u16* __restrict__ xh2,
    const u16* __restrict__ ctxTA,   // stream 1 uses ctx2^T
    const u16* __restrict__ ctxTB,   // stream 2 uses ctx1^T
    float* __restrict__ out)
{
    int id = blockIdx.x;
    int s = id >> 10;
    int r = id & 1023;
    int b = r >> 8;
    int h = (r >> 4) & 15;
    int rc = r & 15;
    const u16* xh = s ? xh2 : xh1;
    const u16* ctxT = s ? ctxTB : ctxTA;
    float* o = out + (size_t)s * 16777216;

    int tid = threadIdx.x, lane = tid & 63, w = tid >> 6;
    int fr = lane & 15, fq = lane >> 4;
    size_t rowbase = (size_t)b * 4096 + rc * 256 + w * 64;
    const u16* Ab = xh + rowbase * 1024 + h * 64;
    const u16* Bb = ctxT + ((size_t)(b * 16 + h)) * 4096;

    f32x4_t acc[4][4];
#pragma unroll
    for (int m = 0; m < 4; ++m)
#pragma unroll
        for (int n = 0; n < 4; ++n) acc[m][n] = (f32x4_t)(0.0f);

#pragma unroll
    for (int ks = 0; ks < 2; ++ks) {
        bf16x8_t a[4], bfr[4];
#pragma unroll
        for (int m = 0; m < 4; ++m)
            a[m] = *(const bf16x8_t*)(Ab + (size_t)(m * 16 + fr) * 1024 + ks * 32 + fq * 8);
#pragma unroll
        for (int n = 0; n < 4; ++n)
            bfr[n] = *(const bf16x8_t*)(Bb + (n * 16 + fr) * 64 + ks * 32 + fq * 8);
#pragma unroll
        for (int m = 0; m < 4; ++m)
#pragma unroll
            for (int n = 0; n < 4; ++n)
                acc[m][n] = __builtin_amdgcn_mfma_f32_16x16x32_bf16(a[m], bfr[n], acc[m][n], 0, 0, 0);
    }

#pragma unroll
    for (int m = 0; m < 4; ++m) {
#pragma unroll
        for (int n = 0; n < 4; ++n) {
            int col = h * 64 + n * 16 + fr;
#pragma unroll
            for (int rr = 0; rr < 4; ++rr) {
                size_t row = rowbase + m * 16 + fq * 4 + rr;
                o[row * 1024 + col] = acc[m][n][rr];
            }
        }
    }
}

// ---------------- host ----------------

extern "C" void kernel_launch(void* const* d_in, const int* in_sizes, int n_in,
                              void* d_out, int out_size, void* d_ws, size_t ws_size,
                              hipStream_t stream)
{
    (void)in_sizes; (void)n_in; (void)out_size; (void)ws_size;
    const float* x1   = (const float*)d_in[0];
    const float* x2   = (const float*)d_in[1];
    const float* Wkv1 = (const float*)d_in[2];
    const float* Wkv2 = (const float*)d_in[3];
    const float* g1w1 = (const float*)d_in[4];
    const float* g1b1 = (const float*)d_in[5];
    const float* g1w2 = (const float*)d_in[6];
    const float* g1b2 = (const float*)d_in[7];
    const float* g2w1 = (const float*)d_in[8];
    const float* g2b1 = (const float*)d_in[9];
    const float* g2w2 = (const float*)d_in[10];
    const float* g2b2 = (const float*)d_in[11];
    float* out = (float*)d_out;

    char* ws = (char*)d_ws;
    size_t off = 0;
    auto alloc = [&](size_t b) { void* p = ws + off; off += (b + 255) & ~(size_t)255; return p; };
    const size_t NTOK = 16384;
    u16* xh1   = (u16*)alloc(NTOK * 1024 * 2);
    u16* xh2   = (u16*)alloc(NTOK * 1024 * 2);
    u16* wkv1h = (u16*)alloc((size_t)2048 * 1024 * 2);
    u16* wkv1l = (u16*)alloc((size_t)2048 * 1024 * 2);
    u16* wkv2h = (u16*)alloc((size_t)2048 * 1024 * 2);
    u16* wkv2l = (u16*)alloc((size_t)2048 * 1024 * 2);
    u16* g1w1t = (u16*)alloc((size_t)1024 * 1024 * 2);
    u16* g1w2t = (u16*)alloc((size_t)1024 * 1024 * 2);
    u16* g2w1t = (u16*)alloc((size_t)1024 * 1024 * 2);
    u16* g2w2t = (u16*)alloc((size_t)1024 * 1024 * 2);
    u16* hbuf  = (u16*)alloc(NTOK * 1024 * 2);
    float* gate = (float*)alloc(NTOK * 1024 * 4);  // gate, then vg in place
    float* kbuf = (float*)alloc(NTOK * 1024 * 4);
    float* part = (float*)alloc((size_t)8 * 64 * 64 * 64 * 4);
    u16* ctxT1 = (u16*)alloc((size_t)64 * 64 * 64 * 2);
    u16* ctxT2 = (u16*)alloc((size_t)64 * 64 * 64 * 2);

    // weights (merged launches)
    cast_wt_split2_kernel<<<dim3(64, 32, 2), 256, 0, stream>>>(Wkv1, Wkv2,
                                                               wkv1h, wkv1l, wkv2h, wkv2l, 1024, 2048);
    cast_wt4_kernel<<<dim3(32, 32, 4), 256, 0, stream>>>(g1w1, g1w2, g2w1, g2w2,
                                                         g1w1t, g1w2t, g2w1t, g2w2t, 1024, 1024);
    cast_x2_kernel<<<2048, 256, 0, stream>>>(x1, x2, xh1, xh2, (int)(NTOK * 1024 / 4));

    // ---- stream 1 ----
    gemm128_kernel<0><<<dim3(128, 8), 256, 0, stream>>>(xh1, g1w1t, nullptr, g1b1,
                                                        hbuf, nullptr, nullptr, nullptr, 1024);
    gemm128_kernel<1><<<dim3(128, 8), 256, 0, stream>>>(hbuf, g1w2t, nullptr, g1b2,
                                                        nullptr, gate, nullptr, nullptr, 1024);
    gemm128_kernel<2><<<dim3(128, 16), 256, 0, stream>>>(xh1, wkv1h, wkv1l, nullptr,
                                                         nullptr, nullptr, gate, kbuf, 2048);
    ctx_part_kernel<<<512, 256, 0, stream>>>(kbuf, gate, part);
    softmax_ctx_kernel<<<64, 256, 0, stream>>>(part, ctxT1);

    // ---- stream 2 ----
    gemm128_kernel<0><<<dim3(128, 8), 256, 0, stream>>>(xh2, g2w1t, nullptr, g2b1,
                                                        hbuf, nullptr, nullptr, nullptr, 1024);
    gemm128_kernel<1><<<dim3(128, 8), 256, 0, stream>>>(hbuf, g2w2t, nullptr, g2b2,
                                                        nullptr, gate, nullptr, nullptr, 1024);
    gemm128_kernel<2><<<dim3(128, 16), 256, 0, stream>>>(xh2, wkv2h, wkv2l, nullptr,
                                                         nullptr, nullptr, gate, kbuf, 2048);
    ctx_part_kernel<<<512, 256, 0, stream>>>(kbuf, gate, part);
    softmax_ctx_kernel<<<64, 256, 0, stream>>>(part, ctxT2);

    // ---- outputs, both streams (cross: o1 uses ctx2, o2 uses ctx1) ----
    out_mfma_kernel<<<2048, 256, 0, stream>>>(xh1, xh2, ctxT2, ctxT1, out);
}